// Round 1
// baseline (726.343 us; speedup 1.0000x reference)
//
#include <hip/hip_runtime.h>
#include <hip/hip_fp16.h>

#define NB 512   // batch
#define NT 512   // time steps
#define NL 126   // labels
#define NS 128   // states (start=126, end=127)
#define SIGMA 0.0625f   // lagged-normalizer target scale (1/16)

typedef _Float16 h2 __attribute__((ext_vector_type(2)));

static __device__ __forceinline__ int pk_from(float a, float b) {
  return __builtin_bit_cast(int, __builtin_amdgcn_cvt_pkrtz(a, b));
}
// guaranteed-packed fp16 ops on int-carried pairs
static __device__ __forceinline__ int pkmul(int a, int b) {
  int d; asm("v_pk_mul_f16 %0, %1, %2" : "=v"(d) : "v"(a), "v"(b)); return d;
}
static __device__ __forceinline__ int pkmax(int a, int b) {
  int d; asm("v_pk_max_f16 %0, %1, %2" : "=v"(d) : "v"(a), "v"(b)); return d;
}
static __device__ __forceinline__ int pkadd(int a, int b) {
  int d; asm("v_pk_add_f16 %0, %1, %2" : "=v"(d) : "v"(a), "v"(b)); return d;
}
// swap lane pairs (0<->1, 2<->3): quad_perm [1,0,3,2], single v_mov_b32_dpp
static __device__ __forceinline__ int dppswap(int x) {
  int d;
  asm("v_mov_b32_dpp %0, %1 quad_perm:[1,0,3,2] row_mask:0xf bank_mask:0xf"
      : "=v"(d) : "v"(x));
  return d;
}

// wave64 add-reduce to lane 63, ONE instruction per stage (v_add_f32_dpp).
// Invalid-source lanes read 0 (bound_ctrl) / masked rows keep dst -> same
// numeric tree as the old update_dpp(0,...) macro, bit-identical.
#define WAVE_ADD(x) do { \
  asm("v_add_f32_dpp %0, %0, %0 row_shr:1  row_mask:0xf bank_mask:0xf bound_ctrl:0" : "+v"(x)); \
  asm("v_add_f32_dpp %0, %0, %0 row_shr:2  row_mask:0xf bank_mask:0xf bound_ctrl:0" : "+v"(x)); \
  asm("v_add_f32_dpp %0, %0, %0 row_shr:4  row_mask:0xf bank_mask:0xf bound_ctrl:0" : "+v"(x)); \
  asm("v_add_f32_dpp %0, %0, %0 row_shr:8  row_mask:0xf bank_mask:0xf bound_ctrl:0" : "+v"(x)); \
  asm("v_add_f32_dpp %0, %0, %0 row_bcast:15 row_mask:0xa bank_mask:0xf bound_ctrl:0" : "+v"(x)); \
  asm("v_add_f32_dpp %0, %0, %0 row_bcast:31 row_mask:0xc bank_mask:0xf bound_ctrl:0" : "+v"(x)); \
} while (0)

// 256 threads (4 waves) per block, TWO batch elements per block (in-wave ILP:
// each wave interleaves two independent recurrence chains so LDS latency,
// log/rcp chains and DPP-reduce latency of one stream hide under the other's
// VALU work — 1 block/CU, 1 wave/SIMD by design). Lane pair (2c,2c+1) of wave
// w owns column 32w+c; each lane covers 64 rows (tab = 32 packed VGPRs shared
// by both streams). Single barrier per step serves both batches; normalizer Z
// lagged one step (R5 math, absmax 0.0). Per-batch math identical to the
// 634us single-batch kernel.
__global__ __launch_bounds__(256) void crf_kernel(
    const float* __restrict__ emissions,   // [NB, NT, NL]
    const int*   __restrict__ labels,      // [NB, NT]
    const float* __restrict__ trans,       // [NS, NS]
    float*       __restrict__ out)
{
  const int bid = blockIdx.x;
  const int b0  = 2 * bid;
  const int b1  = 2 * bid + 1;
  const int tid = threadIdx.x;
  const int wv  = tid >> 6;              // wave 0..3
  const int ln  = tid & 63;
  const int col = (wv << 5) | (ln >> 1); // column 0..127
  const int rh  = ln & 1;                // row half: rows [rh*64, rh*64+64)

  __shared__ __align__(16) _Float16 u_sh[2][2 * NS];   // [stream][pingpong*NS]
  __shared__ __align__(16) float sPart[2][2][4];       // [stream][slot][wave]
  __shared__ __align__(16) float zPart[2][2][4];
  __shared__ float fin[2][4];

  const float* emA  = emissions + (size_t)b0 * NT * NL;
  const float* emB  = emissions + (size_t)b1 * NT * NL;
  const int*   labA = labels + b0 * NT;
  const int*   labB = labels + b1 * NT;

  // ---- per-column max tau (exact fp32, shared by both streams) ----
  float tau = -3.0e38f;
  for (int i = 0; i < NS; i++) tau = fmaxf(tau, trans[i * NS + col]);

  // ---- tab[k] = rows (rh*64+2k, rh*64+2k+1) of exp(T[.][col]-tau) ----
  int tab[32];
  #pragma unroll
  for (int k = 0; k < 32; k++) {
    int row = rh * 64 + 2 * k;
    float t0 = __expf(trans[row * NS + col] - tau);
    float t1 = __expf(trans[(row + 1) * NS + col] - tau);
    tab[k] = pk_from(t0, t1);
  }

  // ---- gold path partials (2 timesteps per thread per stream) ----
  float realpA = 0.f, realpB = 0.f;
  #pragma unroll
  for (int q = 0; q < NT / 256; q++) {
    int t  = tid + q * 256;
    int la = labA[t];
    int na = (t + 1 < NT) ? labA[t + 1] : (NL + 1);
    realpA += emA[t * NL + la] + trans[la * NS + na];
    int lb = labB[t];
    int nb = (t + 1 < NT) ? labB[t + 1] : (NL + 1);
    realpB += emB[t * NL + lb] + trans[lb * NS + nb];
  }
  if (tid == 0) {
    realpA += trans[NL * NS + labA[0]];
    realpB += trans[NL * NS + labB[0]];
  }

  // ---- init: v = delta at start state, buffer 0 (both streams) ----
  if (tid < NS) {
    _Float16 d = (_Float16)((tid == NL) ? 1.f : 0.f);
    u_sh[0][tid] = d; u_sh[0][NS + tid] = (_Float16)0.f;
    u_sh[1][tid] = d; u_sh[1][NS + tid] = (_Float16)0.f;
  }
  float QA = 0.f, CcA = 0.f, QB = 0.f, CcB = 0.f;
  float emcA = (col < NL) ? emA[col] : 0.f;        // rolling 2-deep prefetch
  float emnA = (col < NL) ? emA[NL + col] : 0.f;
  float emcB = (col < NL) ? emB[col] : 0.f;
  float emnB = (col < NL) ? emB[NL + col] : 0.f;
  __syncthreads();

  for (int t = 0; t <= NT; t++) {
    const int sl = t & 1;

    // ---- off-path: lagged scalars from step t-1 (slot t&1), both streams ----
    float rA, rB;
    if (t > 0) {
      const float4 spA = *(const float4*)sPart[0][sl];
      const float4 zpA = *(const float4*)zPart[0][sl];
      const float4 spB = *(const float4*)sPart[1][sl];
      const float4 zpB = *(const float4*)zPart[1][sl];
      float SA = 0.5f * ((spA.x + spA.y) + (spA.z + spA.w));  // 0.5: pair-dup
      float ZA = 0.5f * ((zpA.x + zpA.y) + (zpA.z + zpA.w));
      float SB = 0.5f * ((spB.x + spB.y) + (spB.z + spB.w));
      float ZB = 0.5f * ((zpB.x + zpB.y) + (zpB.z + zpB.w));
      CcA += __logf(SA);
      QA  += __logf(ZA);
      CcB += __logf(SB);
      QB  += __logf(ZB);
      rA = SIGMA * __builtin_amdgcn_rcpf(ZA);
      rB = SIGMA * __builtin_amdgcn_rcpf(ZB);
    } else {
      rA = SIGMA; rB = SIGMA;                // Z(init) = 1
    }

    // ---- off-path: g = exp(obs + tau) from prefetched emissions ----
    float obsA, obsB;
    if (t < NT) {
      obsA = (col < NL) ? emcA : -1000.f;
      obsB = (col < NL) ? emcB : -1000.f;
    } else {
      obsA = (col == NL + 1) ? 0.f : -1000.f;
      obsB = obsA;
    }
    float gA = __expf(obsA + tau);
    float gB = __expf(obsB + tau);
    float efA = (t + 2 < NT && col < NL) ? emA[(t + 2) * NL + col] : 0.f;
    float efB = (t + 2 < NT && col < NL) ? emB[(t + 2) * NL + col] : 0.f;
    emcA = emnA; emnA = efA;
    emcB = emnB; emnB = efB;

    // ---- issue both streams' u reads up front (16x ds_read_b128) ----
    const int4* upA = (const int4*)(&u_sh[0][sl * NS]) + rh * 8;
    const int4* upB = (const int4*)(&u_sh[1][sl * NS]) + rh * 8;
    int4 ua[8], ub[8];
    #pragma unroll
    for (int k = 0; k < 8; k++) ua[k] = upA[k];
    #pragma unroll
    for (int k = 0; k < 8; k++) ub[k] = upB[k];

    // ---- critical path, stream A: 64 rows of column col ----
    int hA0 = 0, hB0 = 0, hC0 = 0, hD0 = 0;
    int sA0 = 0, sB0 = 0, sC0 = 0, sD0 = 0;
    #pragma unroll
    for (int kk = 0; kk < 8; kk++) {
      int m0 = pkmul(ua[kk].x, tab[4 * kk + 0]);
      int m1 = pkmul(ua[kk].y, tab[4 * kk + 1]);
      int m2 = pkmul(ua[kk].z, tab[4 * kk + 2]);
      int m3 = pkmul(ua[kk].w, tab[4 * kk + 3]);
      hA0 = pkmax(hA0, m0); hB0 = pkmax(hB0, m1);
      hC0 = pkmax(hC0, m2); hD0 = pkmax(hD0, m3);
      sA0 = pkadd(sA0, m0); sB0 = pkadd(sB0, m1);
      sC0 = pkadd(sC0, m2); sD0 = pkadd(sD0, m3);
    }
    int hvA = pkmax(pkmax(hA0, hB0), pkmax(hC0, hD0));
    int svA = pkadd(pkadd(sA0, sB0), pkadd(sC0, sD0));
    hvA = pkmax(hvA, dppswap(hvA));       // combine row halves across lane pair
    svA = pkadd(svA, dppswap(svA));
    h2 hhA = __builtin_bit_cast(h2, hvA);
    h2 ssA = __builtin_bit_cast(h2, svA);
    float hAf = fmaxf(fmaxf((float)hhA.x, (float)hhA.y), 1e-30f);
    float sAf = (float)ssA.x + (float)ssA.y;
    float wA = hAf * gA;
    float vA = wA * rA;
    u_sh[0][((t + 1) & 1) * NS + col] = (_Float16)vA;
    float cSA = sAf * __builtin_amdgcn_rcpf(hAf);
    float cVA = vA;

    // ---- critical path, stream B ----
    int hA1 = 0, hB1 = 0, hC1 = 0, hD1 = 0;
    int sA1 = 0, sB1 = 0, sC1 = 0, sD1 = 0;
    #pragma unroll
    for (int kk = 0; kk < 8; kk++) {
      int m0 = pkmul(ub[kk].x, tab[4 * kk + 0]);
      int m1 = pkmul(ub[kk].y, tab[4 * kk + 1]);
      int m2 = pkmul(ub[kk].z, tab[4 * kk + 2]);
      int m3 = pkmul(ub[kk].w, tab[4 * kk + 3]);
      hA1 = pkmax(hA1, m0); hB1 = pkmax(hB1, m1);
      hC1 = pkmax(hC1, m2); hD1 = pkmax(hD1, m3);
      sA1 = pkadd(sA1, m0); sB1 = pkadd(sB1, m1);
      sC1 = pkadd(sC1, m2); sD1 = pkadd(sD1, m3);
    }
    int hvB = pkmax(pkmax(hA1, hB1), pkmax(hC1, hD1));
    int svB = pkadd(pkadd(sA1, sB1), pkadd(sC1, sD1));
    hvB = pkmax(hvB, dppswap(hvB));
    svB = pkadd(svB, dppswap(svB));
    h2 hhB = __builtin_bit_cast(h2, hvB);
    h2 ssB = __builtin_bit_cast(h2, svB);
    float hBf = fmaxf(fmaxf((float)hhB.x, (float)hhB.y), 1e-30f);
    float sBf = (float)ssB.x + (float)ssB.y;
    float wB = hBf * gB;
    float vB = wB * rB;
    u_sh[1][((t + 1) & 1) * NS + col] = (_Float16)vB;
    float cSB = sBf * __builtin_amdgcn_rcpf(hBf);
    float cVB = vB;

    // ---- off-path: 4 independent reduction chains (interleave in scheduler) ----
    WAVE_ADD(cSA);
    WAVE_ADD(cVA);
    WAVE_ADD(cSB);
    WAVE_ADD(cVB);
    if (ln == 63) {
      const int s2 = (t + 1) & 1;
      sPart[0][s2][wv] = cSA; zPart[0][s2][wv] = cVA;
      sPart[1][s2][wv] = cSB; zPart[1][s2][wv] = cVB;
    }
    __syncthreads();                   // the ONLY barrier per step (2 batches)
  }

  // ---- final scalars of step NT (slot (NT+1)&1 = 1), both streams ----
  {
    const float4 spA = *(const float4*)sPart[0][1];
    const float4 zpA = *(const float4*)zPart[0][1];
    const float4 spB = *(const float4*)sPart[1][1];
    const float4 zpB = *(const float4*)zPart[1][1];
    float SA = 0.5f * ((spA.x + spA.y) + (spA.z + spA.w));
    float ZA = 0.5f * ((zpA.x + zpA.y) + (zpA.z + zpA.w));
    float SB = 0.5f * ((spB.x + spB.y) + (spB.z + spB.w));
    float ZB = 0.5f * ((zpB.x + zpB.y) + (zpB.z + zpB.w));
    CcA += __logf(SA);
    QA  += __logf(ZA);
    CcB += __logf(SB);
    QB  += __logf(ZB);
  }

  // total = Cc + Q + (NT+1)*log(1/SIGMA) per stream
  WAVE_ADD(realpA);
  WAVE_ADD(realpB);
  if (ln == 63) { fin[0][wv] = realpA; fin[1][wv] = realpB; }
  __syncthreads();
  if (tid == 0) {
    const float CONST = 513.f * 2.772588722f;   // (NT+1) * log 16
    float totA  = CcA + QA + CONST;
    float totB  = CcB + QB + CONST;
    float realA = (fin[0][0] + fin[0][1]) + (fin[0][2] + fin[0][3]);
    float realB = (fin[1][0] + fin[1][1]) + (fin[1][2] + fin[1][3]);
    atomicAdd(out, (totA - realA) + (totB - realB));
  }
}

extern "C" void kernel_launch(void* const* d_in, const int* in_sizes, int n_in,
                              void* d_out, int out_size, void* d_ws, size_t ws_size,
                              hipStream_t stream) {
  const float* em  = (const float*)d_in[0];
  const int*   lab = (const int*)d_in[1];
  const float* tr  = (const float*)d_in[2];
  (void)hipMemsetAsync(d_out, 0, sizeof(float), stream);
  crf_kernel<<<NB / 2, 256, 0, stream>>>(em, lab, tr, (float*)d_out);
}